// Round 4
// baseline (891.056 us; speedup 1.0000x reference)
//
#include <hip/hip_runtime.h>
#include <hip/hip_bf16.h>

typedef unsigned short u16;
typedef unsigned int   u32;
using bf16x8 = __attribute__((ext_vector_type(8))) short;
using f32x4  = __attribute__((ext_vector_type(4))) float;

#define AS1 __attribute__((address_space(1)))
#define AS3 __attribute__((address_space(3)))

static constexpr int S_   = 1024;
static constexpr int D_   = 4096;
static constexpr int H_   = 32;
static constexpr int KVH_ = 8;
static constexpr int HD_  = 128;
static constexpr int NQKV = H_*HD_ + 2*KVH_*HD_;   // 6144

__device__ __forceinline__ u16 f2bf(float f) {
  union { float f; u32 u; } v; v.f = f;
  u32 r = v.u + 0x7FFFu + ((v.u >> 16) & 1u);      // RTNE
  return (u16)(r >> 16);
}

// ---------------- x f32 -> bf16 ----------------
__global__ void k_convert(const float* __restrict__ src, u16* __restrict__ dst, int n4) {
  int i = blockIdx.x * blockDim.x + threadIdx.x;
  if (i >= n4) return;
  float4 v = ((const float4*)src)[i];
  ushort4 o;
  o.x = f2bf(v.x); o.y = f2bf(v.y); o.z = f2bf(v.z); o.w = f2bf(v.w);
  ((ushort4*)dst)[i] = o;
}

// ---------------- W [K][N] f32 -> Wt [N][K] bf16 ----------------
__global__ void k_transpose_w(const float* __restrict__ src, u16* __restrict__ dst,
                              int K, int N) {
  __shared__ float t[32][33];
  int k0 = blockIdx.y * 32, n0 = blockIdx.x * 32;
  int tx = threadIdx.x, ty = threadIdx.y;           // (32,8)
#pragma unroll
  for (int i = 0; i < 4; ++i)
    t[ty + i*8][tx] = src[(size_t)(k0 + ty + i*8) * N + n0 + tx];
  __syncthreads();
#pragma unroll
  for (int i = 0; i < 4; ++i)
    dst[(size_t)(n0 + ty + i*8) * K + k0 + tx] = f2bf(t[tx][ty + i*8]);
}

// ---------------- V [BG][S][HD] bf16 -> Vt [BG][HD][S] bf16 ----------------
__global__ void k_transpose_v(const u16* __restrict__ src, u16* __restrict__ dst) {
  __shared__ u16 t[32][33];
  int bg = blockIdx.z;
  int s0 = blockIdx.x * 32, h0 = blockIdx.y * 32;
  src += (size_t)bg * S_ * HD_;
  dst += (size_t)bg * S_ * HD_;
  int tx = threadIdx.x, ty = threadIdx.y;
#pragma unroll
  for (int i = 0; i < 4; ++i)
    t[ty + i*8][tx] = src[(size_t)(s0 + ty + i*8) * HD_ + h0 + tx];
  __syncthreads();
#pragma unroll
  for (int i = 0; i < 4; ++i)
    dst[(size_t)(h0 + ty + i*8) * S_ + s0 + tx] = t[tx][ty + i*8];
}

// ---------------- RoPE tables: cos/sin [S][64] f32 ----------------
__global__ void k_rope(const int* __restrict__ sidx, float* __restrict__ cosd,
                       float* __restrict__ sind) {
  int i = blockIdx.x * blockDim.x + threadIdx.x;    // S*64
  int s = i >> 6, d = i & 63;
  float pos  = (float)sidx[s];
  float invf = expf(-0.21586735246819178f * (float)d);  // 1e6^(-d/64)
  float ph   = pos * invf;
  cosd[i] = cosf(ph);
  sind[i] = sinf(ph);
}

// ---------------- 128x128 bf16 GEMM: C[M][N] = A[M][K] * Bt[N][K]^T ----------------
__global__ __launch_bounds__(256) void k_gemm(
    const u16* __restrict__ A, const u16* __restrict__ Bt,
    float* __restrict__ C, int M, int N, int K)
{
  __shared__ char As[16384];
  __shared__ char Bs[16384];
  int tid = threadIdx.x, lane = tid & 63, wid = tid >> 6;
  int l15 = lane & 15, l4 = lane >> 4;
  int m0 = blockIdx.y * 128, n0 = blockIdx.x * 128;
  int wr = wid >> 1, wc = wid & 1;
  f32x4 acc[4][4];
#pragma unroll
  for (int i = 0; i < 4; ++i)
#pragma unroll
    for (int j = 0; j < 4; ++j) acc[i][j] = (f32x4){0.f,0.f,0.f,0.f};

  int arow[4], aslot[4];
#pragma unroll
  for (int q = 0; q < 4; ++q) {
    int o = (wid*4 + q)*1024 + lane*16;
    int row = o >> 7, ss = (o >> 4) & 7;
    arow[q] = row; aslot[q] = ss ^ (row & 7);
  }

  for (int kt = 0; kt < K; kt += 64) {
#pragma unroll
    for (int q = 0; q < 4; ++q) {
      __builtin_amdgcn_global_load_lds(
          (AS1 void*)(A  + (size_t)(m0 + arow[q]) * K + kt + aslot[q]*8),
          (AS3 void*)(As + (wid*4 + q)*1024), 16, 0, 0);
      __builtin_amdgcn_global_load_lds(
          (AS1 void*)(Bt + (size_t)(n0 + arow[q]) * K + kt + aslot[q]*8),
          (AS3 void*)(Bs + (wid*4 + q)*1024), 16, 0, 0);
    }
    __syncthreads();
#pragma unroll
    for (int kk = 0; kk < 2; ++kk) {
      int ks = kk*4 + l4;
      bf16x8 af[4], bfv[4];
#pragma unroll
      for (int i = 0; i < 4; ++i) {
        int row = wr*64 + i*16 + l15;
        af[i] = *(const bf16x8*)(As + row*128 + ((ks ^ (row & 7)) << 4));
      }
#pragma unroll
      for (int j = 0; j < 4; ++j) {
        int row = wc*64 + j*16 + l15;
        bfv[j] = *(const bf16x8*)(Bs + row*128 + ((ks ^ (row & 7)) << 4));
      }
#pragma unroll
      for (int i = 0; i < 4; ++i)
#pragma unroll
        for (int j = 0; j < 4; ++j)
          acc[i][j] = __builtin_amdgcn_mfma_f32_16x16x32_bf16(af[i], bfv[j], acc[i][j], 0, 0, 0);
    }
    __syncthreads();
  }
#pragma unroll
  for (int i = 0; i < 4; ++i)
#pragma unroll
    for (int j = 0; j < 4; ++j) {
      int r0 = m0 + wr*64 + i*16 + l4*4;
      int c0 = n0 + wc*64 + j*16 + l15;
#pragma unroll
      for (int r = 0; r < 4; ++r)
        C[(size_t)(r0 + r) * N + c0] = acc[i][j][r];
    }
}

// ---------------- bias + RoPE + pack to [B][H][S][HD] bf16 ----------------
__global__ void k_pack(const float* __restrict__ Cq,
                       const float* __restrict__ bq, const float* __restrict__ bk,
                       const float* __restrict__ bv,
                       const float* __restrict__ cosd, const float* __restrict__ sind,
                       u16* __restrict__ qb, u16* __restrict__ kb, u16* __restrict__ vb) {
  int t = blockIdx.x;
  int b = t >> 10, s = t & 1023;
  const float* row = Cq + (size_t)t * NQKV;
  const float* cs = cosd + s*64;
  const float* sn = sind + s*64;
  const float qscale = 0.08838834764831845f;  // 1/sqrt(HD)
  for (int c = threadIdx.x; c < H_*HD_; c += blockDim.x) {
    int h = c >> 7, d = c & 127;
    float v = row[c] + bq[c];
    float o;
    if (d < 64) { float p = row[c + 64] + bq[c + 64]; o = v*cs[d]    - p*sn[d]; }
    else        { float p = row[c - 64] + bq[c - 64]; o = v*cs[d-64] + p*sn[d-64]; }
    qb[(((size_t)b*H_ + h)*S_ + s)*HD_ + d] = f2bf(o * qscale);
  }
  for (int c = threadIdx.x; c < KVH_*HD_; c += blockDim.x) {
    int g = c >> 7, d = c & 127;
    float v = row[H_*HD_ + c] + bk[c];
    float o;
    if (d < 64) { float p = row[H_*HD_ + c + 64] + bk[c + 64]; o = v*cs[d]    - p*sn[d]; }
    else        { float p = row[H_*HD_ + c - 64] + bk[c - 64]; o = v*cs[d-64] + p*sn[d-64]; }
    size_t idx = (((size_t)b*KVH_ + g)*S_ + s)*HD_ + d;
    kb[idx] = f2bf(o);
    vb[idx] = f2bf(row[H_*HD_ + KVH_*HD_ + c] + bv[c]);
  }
}

// ---------------- causal GQA flash attention (dual-tile interleaved, direct global) ---
// grid (8, H, B); block = 4 waves, NO barriers. Wave w owns q-rows [t*64+w*16, +16) of
// BOTH tiles tA=bx and tB=15-bx, advanced in one kv loop (A predicated by kv<=tA).
// K/V fragments load direct from global (L2-resident: 0.5 MB per (b,g) group) and feed
// 2 MFMAs each; two independent softmax/PV chains give in-wave ILP.
__device__ __forceinline__ void sm_step(f32x4 (&sc)[4], float (&mrow)[4], float (&lrow)[4],
                                        f32x4 (&o)[8], char* Pw, int l15, int l4) {
  float f[4];
#pragma unroll
  for (int r = 0; r < 4; ++r) {
    float mx = fmaxf(fmaxf(sc[0][r], sc[1][r]), fmaxf(sc[2][r], sc[3][r]));
    mx = fmaxf(mx, __shfl_xor(mx, 1));
    mx = fmaxf(mx, __shfl_xor(mx, 2));
    mx = fmaxf(mx, __shfl_xor(mx, 4));
    mx = fmaxf(mx, __shfl_xor(mx, 8));
    float nm = fmaxf(mrow[r], mx);
    f[r] = __expf(mrow[r] - nm);
    mrow[r] = nm;
  }
  float rs[4] = {0.f,0.f,0.f,0.f};
#pragma unroll
  for (int ct = 0; ct < 4; ++ct)
#pragma unroll
    for (int r = 0; r < 4; ++r) {
      float p = __expf(sc[ct][r] - mrow[r]);
      rs[r] += p;
      int row = l4*4 + r, col = ct*16 + l15;
      int byte = row*128 + (((col >> 3) ^ (row & 7)) << 4) + (col & 7)*2;
      *(u16*)(Pw + byte) = f2bf(p);
    }
#pragma unroll
  for (int r = 0; r < 4; ++r) {
    float sum = rs[r];
    sum += __shfl_xor(sum, 1);
    sum += __shfl_xor(sum, 2);
    sum += __shfl_xor(sum, 4);
    sum += __shfl_xor(sum, 8);
    lrow[r] = lrow[r]*f[r] + sum;
  }
#pragma unroll
  for (int n = 0; n < 8; ++n)
#pragma unroll
    for (int r = 0; r < 4; ++r) o[n][r] *= f[r];
}

__device__ __forceinline__ void write_o(const f32x4 (&o)[8], const float (&lrow)[4],
                                        u16* __restrict__ AOh, int qrow0, int l15, int l4) {
#pragma unroll
  for (int n = 0; n < 8; ++n)
#pragma unroll
    for (int r = 0; r < 4; ++r) {
      int srow = qrow0 + l4*4 + r;
      AOh[(size_t)srow * (H_*HD_) + n*16 + l15] = f2bf(o[n][r] / lrow[r]);
    }
}

__global__ __launch_bounds__(256, 2) void k_attn(
    const u16* __restrict__ Q, const u16* __restrict__ Kc,
    const u16* __restrict__ Vt, u16* __restrict__ AO)
{
  int tA = blockIdx.x, tB = 15 - tA;          // paired q-tiles: balanced work
  int h = blockIdx.y, b = blockIdx.z, g = h >> 2;
  int tid = threadIdx.x, lane = tid & 63, w = tid >> 6;
  int l15 = lane & 15, l4 = lane >> 4;
  const u16* Qh = Q  + ((size_t)b*H_   + h) * S_ * HD_;
  const u16* Kp = Kc + ((size_t)b*KVH_ + g) * S_ * HD_;
  const u16* Vp = Vt + ((size_t)b*KVH_ + g) * (size_t)HD_ * S_;   // [HD][S]
  u16* AOh = AO + ((size_t)b*S_) * (H_*HD_) + h*HD_;

  __shared__ u16 Pl[8][1024];                 // 4 waves x 2 tiles, per-wave private
  char* PwA = (char*)&Pl[w*2 + 0][0];
  char* PwB = (char*)&Pl[w*2 + 1][0];

  bf16x8 qfA[4], qfB[4];
#pragma unroll
  for (int kc = 0; kc < 4; ++kc) {
    qfA[kc] = *(const bf16x8*)(Qh + (size_t)(tA*64 + w*16 + l15)*HD_ + kc*32 + l4*8);
    qfB[kc] = *(const bf16x8*)(Qh + (size_t)(tB*64 + w*16 + l15)*HD_ + kc*32 + l4*8);
  }

  f32x4 oA[8], oB[8];
#pragma unroll
  for (int n = 0; n < 8; ++n) { oA[n] = (f32x4){0.f,0.f,0.f,0.f}; oB[n] = (f32x4){0.f,0.f,0.f,0.f}; }
  float mA[4] = {-3e38f,-3e38f,-3e38f,-3e38f}, lA[4] = {0.f,0.f,0.f,0.f};
  float mB[4] = {-3e38f,-3e38f,-3e38f,-3e38f}, lB[4] = {0.f,0.f,0.f,0.f};

  for (int kv = 0; kv <= tB; ++kv) {
    int kvb = kv * 64;
    bool aA = (kv <= tA);

    f32x4 scA[4], scB[4];
#pragma unroll
    for (int ct = 0; ct < 4; ++ct) {
      bf16x8 kf[4];
#pragma unroll
      for (int kc = 0; kc < 4; ++kc)
        kf[kc] = *(const bf16x8*)(Kp + (size_t)(kvb + ct*16 + l15)*HD_ + kc*32 + l4*8);
      f32x4 a4 = (f32x4){0.f,0.f,0.f,0.f}, b4 = (f32x4){0.f,0.f,0.f,0.f};
      if (aA) {
#pragma unroll
        for (int kc = 0; kc < 4; ++kc)
          a4 = __builtin_amdgcn_mfma_f32_16x16x32_bf16(qfA[kc], kf[kc], a4, 0, 0, 0);
      }
#pragma unroll
      for (int kc = 0; kc < 4; ++kc)
        b4 = __builtin_amdgcn_mfma_f32_16x16x32_bf16(qfB[kc], kf[kc], b4, 0, 0, 0);
      scA[ct] = a4; scB[ct] = b4;
    }

    if (kv == tA) {
#pragma unroll
      for (int ct = 0; ct < 4; ++ct)
#pragma unroll
        for (int r = 0; r < 4; ++r) {
          int col = kvb + ct*16 + l15;
          int rw  = tA*64 + w*16 + l4*4 + r;
          if (col > rw) scA[ct][r] = -1e9f;
        }
    }
    if (kv == tB) {
#pragma unroll
      for (int ct = 0; ct < 4; ++ct)
#pragma unroll
        for (int r = 0; r < 4; ++r) {
          int col = kvb + ct*16 + l15;
          int rw  = tB*64 + w*16 + l4*4 + r;
          if (col > rw) scB[ct][r] = -1e9f;
        }
    }

    if (aA) sm_step(scA, mA, lA, oA, PwA, l15, l4);
    sm_step(scB, mB, lB, oB, PwB, l15, l4);

#pragma unroll
    for (int kk = 0; kk < 2; ++kk) {
      int pbyte = l15*128 + (((kk*4 + l4) ^ (l15 & 7)) << 4);
      bf16x8 pfA = {};
      if (aA) pfA = *(const bf16x8*)(PwA + pbyte);
      bf16x8 pfB = *(const bf16x8*)(PwB + pbyte);
#pragma unroll
      for (int n = 0; n < 8; ++n) {
        bf16x8 vf = *(const bf16x8*)(Vp + (size_t)(n*16 + l15)*S_ + kvb + kk*32 + l4*8);
        if (aA) oA[n] = __builtin_amdgcn_mfma_f32_16x16x32_bf16(pfA, vf, oA[n], 0, 0, 0);
        oB[n] = __builtin_amdgcn_mfma_f32_16x16x32_bf16(pfB, vf, oB[n], 0, 0, 0);
      }
    }
  }

  write_o(oA, lA, AOh, tA*64 + w*16, l15, l4);
  write_o(oB, lB, AOh, tB*64 + w*16, l15, l4);
}

extern "C" void kernel_launch(void* const* d_in, const int* in_sizes, int n_in,
                              void* d_out, int out_size, void* d_ws, size_t ws_size,
                              hipStream_t stream) {
  (void)in_sizes; (void)n_in; (void)out_size; (void)ws_size;
  const float* x   = (const float*)d_in[0];
  const int*   sid = (const int*)  d_in[1];
  // d_in[2] = cache (dead), d_in[3] = mask (dead: causal re-derived)
  const float* Wq  = (const float*)d_in[4];
  const float* bq  = (const float*)d_in[5];
  const float* Wk  = (const float*)d_in[6];
  const float* bk  = (const float*)d_in[7];
  const float* Wv  = (const float*)d_in[8];
  const float* bv  = (const float*)d_in[9];
  const float* Wo  = (const float*)d_in[10];
  float* out = (float*)d_out;

  char* ws = (char*)d_ws;
  u16*   xb   = (u16*)  (ws);                    // 16 MB (aliased by AO later)
  u16*   WB   = (u16*)  (ws + 16777216);         // 48 MB  [6144][4096]
  u16*   WoT  = (u16*)  (ws + 67108864);         // 32 MB  [4096][4096]
  float* Cq   = (float*)(ws + 100663296);        // 48 MB  [2048][6144]
  u16*   qb   = (u16*)  (ws + 150994944);        // 16 MB  [B][H][S][HD]
  u16*   kb   = (u16*)  (ws + 167772160);        //  4 MB  [B][KVH][S][HD]
  u16*   vb   = (u16*)  (ws + 171966464);        //  4 MB
  u16*   VT   = (u16*)  (ws + 176160768);        //  4 MB  [B][KVH][HD][S]
  float* cosd = (float*)(ws + 180355072);        // 256 KB
  float* sind = (float*)(ws + 180617216);        // 256 KB (total ~181 MB)
  u16*   AO   = xb;                              // attention output reuses xb

  dim3 tb(32, 8);
  k_convert<<<8192, 256, 0, stream>>>(x, xb, (2048*4096)/4);
  k_transpose_w<<<dim3(128,128), tb, 0, stream>>>(Wq, WB, 4096, 4096);
  k_transpose_w<<<dim3( 32,128), tb, 0, stream>>>(Wk, WB + (size_t)4096*4096, 4096, 1024);
  k_transpose_w<<<dim3( 32,128), tb, 0, stream>>>(Wv, WB + (size_t)5120*4096, 4096, 1024);
  k_transpose_w<<<dim3(128,128), tb, 0, stream>>>(Wo, WoT, 4096, 4096);
  k_rope<<<256, 256, 0, stream>>>(sid, cosd, sind);
  k_gemm<<<dim3(48,16), 256, 0, stream>>>(xb, WB, Cq, 2048, NQKV, 4096);
  k_pack<<<2048, 256, 0, stream>>>(Cq, bq, bk, bv, cosd, sind, qb, kb, vb);
  k_transpose_v<<<dim3(32,4,16), tb, 0, stream>>>(vb, VT);
  k_attn<<<dim3(8,32,2), 256, 0, stream>>>(qb, kb, VT, AO);
  k_gemm<<<dim3(32,16), 256, 0, stream>>>(AO, WoT, out, 2048, 4096, 4096);
}

// Round 5
// 472.524 us; speedup vs baseline: 1.8857x; 1.8857x over previous
//
#include <hip/hip_runtime.h>
#include <hip/hip_bf16.h>

typedef unsigned short u16;
typedef unsigned int   u32;
using bf16x8 = __attribute__((ext_vector_type(8))) short;
using f32x4  = __attribute__((ext_vector_type(4))) float;

#define AS1 __attribute__((address_space(1)))
#define AS3 __attribute__((address_space(3)))

static constexpr int S_   = 1024;
static constexpr int D_   = 4096;
static constexpr int H_   = 32;
static constexpr int KVH_ = 8;
static constexpr int HD_  = 128;
static constexpr int NQKV = H_*HD_ + 2*KVH_*HD_;   // 6144

__device__ __forceinline__ u16 f2bf(float f) {
  union { float f; u32 u; } v; v.f = f;
  u32 r = v.u + 0x7FFFu + ((v.u >> 16) & 1u);      // RTNE
  return (u16)(r >> 16);
}

// ---------------- x f32 -> bf16 ----------------
__global__ void k_convert(const float* __restrict__ src, u16* __restrict__ dst, int n4) {
  int i = blockIdx.x * blockDim.x + threadIdx.x;
  if (i >= n4) return;
  float4 v = ((const float4*)src)[i];
  ushort4 o;
  o.x = f2bf(v.x); o.y = f2bf(v.y); o.z = f2bf(v.z); o.w = f2bf(v.w);
  ((ushort4*)dst)[i] = o;
}

// ---------------- W [K][N] f32 -> Wt [N][K] bf16 ----------------
__global__ void k_transpose_w(const float* __restrict__ src, u16* __restrict__ dst,
                              int K, int N) {
  __shared__ float t[32][33];
  int k0 = blockIdx.y * 32, n0 = blockIdx.x * 32;
  int tx = threadIdx.x, ty = threadIdx.y;           // (32,8)
#pragma unroll
  for (int i = 0; i < 4; ++i)
    t[ty + i*8][tx] = src[(size_t)(k0 + ty + i*8) * N + n0 + tx];
  __syncthreads();
#pragma unroll
  for (int i = 0; i < 4; ++i)
    dst[(size_t)(n0 + ty + i*8) * K + k0 + tx] = f2bf(t[tx][ty + i*8]);
}

// ---------------- V [BG][S][HD] bf16 -> Vt [BG][HD][S] bf16 ----------------
__global__ void k_transpose_v(const u16* __restrict__ src, u16* __restrict__ dst) {
  __shared__ u16 t[32][33];
  int bg = blockIdx.z;
  int s0 = blockIdx.x * 32, h0 = blockIdx.y * 32;
  src += (size_t)bg * S_ * HD_;
  dst += (size_t)bg * S_ * HD_;
  int tx = threadIdx.x, ty = threadIdx.y;
#pragma unroll
  for (int i = 0; i < 4; ++i)
    t[ty + i*8][tx] = src[(size_t)(s0 + ty + i*8) * HD_ + h0 + tx];
  __syncthreads();
#pragma unroll
  for (int i = 0; i < 4; ++i)
    dst[(size_t)(h0 + ty + i*8) * S_ + s0 + tx] = t[tx][ty + i*8];
}

// ---------------- RoPE tables: cos/sin [S][64] f32 ----------------
__global__ void k_rope(const int* __restrict__ sidx, float* __restrict__ cosd,
                       float* __restrict__ sind) {
  int i = blockIdx.x * blockDim.x + threadIdx.x;    // S*64
  int s = i >> 6, d = i & 63;
  float pos  = (float)sidx[s];
  float invf = expf(-0.21586735246819178f * (float)d);  // 1e6^(-d/64)
  float ph   = pos * invf;
  cosd[i] = cosf(ph);
  sind[i] = sinf(ph);
}

// ---------------- 128x128 bf16 GEMM: C[M][N] = A[M][K] * Bt[N][K]^T ----------------
__global__ __launch_bounds__(256) void k_gemm(
    const u16* __restrict__ A, const u16* __restrict__ Bt,
    float* __restrict__ C, int M, int N, int K)
{
  __shared__ char As[16384];
  __shared__ char Bs[16384];
  int tid = threadIdx.x, lane = tid & 63, wid = tid >> 6;
  int l15 = lane & 15, l4 = lane >> 4;
  int m0 = blockIdx.y * 128, n0 = blockIdx.x * 128;
  int wr = wid >> 1, wc = wid & 1;
  f32x4 acc[4][4];
#pragma unroll
  for (int i = 0; i < 4; ++i)
#pragma unroll
    for (int j = 0; j < 4; ++j) acc[i][j] = (f32x4){0.f,0.f,0.f,0.f};

  int arow[4], aslot[4];
#pragma unroll
  for (int q = 0; q < 4; ++q) {
    int o = (wid*4 + q)*1024 + lane*16;
    int row = o >> 7, ss = (o >> 4) & 7;
    arow[q] = row; aslot[q] = ss ^ (row & 7);
  }

  for (int kt = 0; kt < K; kt += 64) {
#pragma unroll
    for (int q = 0; q < 4; ++q) {
      __builtin_amdgcn_global_load_lds(
          (AS1 void*)(A  + (size_t)(m0 + arow[q]) * K + kt + aslot[q]*8),
          (AS3 void*)(As + (wid*4 + q)*1024), 16, 0, 0);
      __builtin_amdgcn_global_load_lds(
          (AS1 void*)(Bt + (size_t)(n0 + arow[q]) * K + kt + aslot[q]*8),
          (AS3 void*)(Bs + (wid*4 + q)*1024), 16, 0, 0);
    }
    __syncthreads();
#pragma unroll
    for (int kk = 0; kk < 2; ++kk) {
      int ks = kk*4 + l4;
      bf16x8 af[4], bfv[4];
#pragma unroll
      for (int i = 0; i < 4; ++i) {
        int row = wr*64 + i*16 + l15;
        af[i] = *(const bf16x8*)(As + row*128 + ((ks ^ (row & 7)) << 4));
      }
#pragma unroll
      for (int j = 0; j < 4; ++j) {
        int row = wc*64 + j*16 + l15;
        bfv[j] = *(const bf16x8*)(Bs + row*128 + ((ks ^ (row & 7)) << 4));
      }
#pragma unroll
      for (int i = 0; i < 4; ++i)
#pragma unroll
        for (int j = 0; j < 4; ++j)
          acc[i][j] = __builtin_amdgcn_mfma_f32_16x16x32_bf16(af[i], bfv[j], acc[i][j], 0, 0, 0);
    }
    __syncthreads();
  }
#pragma unroll
  for (int i = 0; i < 4; ++i)
#pragma unroll
    for (int j = 0; j < 4; ++j) {
      int r0 = m0 + wr*64 + i*16 + l4*4;
      int c0 = n0 + wc*64 + j*16 + l15;
#pragma unroll
      for (int r = 0; r < 4; ++r)
        C[(size_t)(r0 + r) * N + c0] = acc[i][j][r];
    }
}

// ---------------- bias + RoPE + pack to [B][H][S][HD] bf16 ----------------
__global__ void k_pack(const float* __restrict__ Cq,
                       const float* __restrict__ bq, const float* __restrict__ bk,
                       const float* __restrict__ bv,
                       const float* __restrict__ cosd, const float* __restrict__ sind,
                       u16* __restrict__ qb, u16* __restrict__ kb, u16* __restrict__ vb) {
  int t = blockIdx.x;
  int b = t >> 10, s = t & 1023;
  const float* row = Cq + (size_t)t * NQKV;
  const float* cs = cosd + s*64;
  const float* sn = sind + s*64;
  const float qscale = 0.08838834764831845f;  // 1/sqrt(HD)
  for (int c = threadIdx.x; c < H_*HD_; c += blockDim.x) {
    int h = c >> 7, d = c & 127;
    float v = row[c] + bq[c];
    float o;
    if (d < 64) { float p = row[c + 64] + bq[c + 64]; o = v*cs[d]    - p*sn[d]; }
    else        { float p = row[c - 64] + bq[c - 64]; o = v*cs[d-64] + p*sn[d-64]; }
    qb[(((size_t)b*H_ + h)*S_ + s)*HD_ + d] = f2bf(o * qscale);
  }
  for (int c = threadIdx.x; c < KVH_*HD_; c += blockDim.x) {
    int g = c >> 7, d = c & 127;
    float v = row[H_*HD_ + c] + bk[c];
    float o;
    if (d < 64) { float p = row[H_*HD_ + c + 64] + bk[c + 64]; o = v*cs[d]    - p*sn[d]; }
    else        { float p = row[H_*HD_ + c - 64] + bk[c - 64]; o = v*cs[d-64] + p*sn[d-64]; }
    size_t idx = (((size_t)b*KVH_ + g)*S_ + s)*HD_ + d;
    kb[idx] = f2bf(o);
    vb[idx] = f2bf(row[H_*HD_ + KVH_*HD_ + c] + bv[c]);
  }
}

// ---------------- causal GQA flash attention (wave-independent 16-row chunks) --------
// Block = 2 independent waves (128 thr). Wave handles chunk pair {c, 63-c} sequentially
// (17-18 kv-units, balanced). Per-chunk kv bound = c>>2. Direct-global K/V (L2-resident,
// proven 34 MB fetch), per-wave private P in LDS, zero barriers, setprio around MFMAs.
// Finer blocks -> more resident waves/SIMD to hide the scattered-load latency.
__device__ __forceinline__ void attn_chunk(
    int chunk, const u16* __restrict__ Qh, const u16* __restrict__ Kp,
    const u16* __restrict__ Vp, u16* __restrict__ AOh, int lane, char* Pw)
{
  int l15 = lane & 15, l4 = lane >> 4;
  int qrow0 = chunk * 16;
  int kvmax = chunk >> 2;

  bf16x8 qf[4];
#pragma unroll
  for (int kc = 0; kc < 4; ++kc)
    qf[kc] = *(const bf16x8*)(Qh + (size_t)(qrow0 + l15)*HD_ + kc*32 + l4*8);

  f32x4 o[8];
#pragma unroll
  for (int n = 0; n < 8; ++n) o[n] = (f32x4){0.f,0.f,0.f,0.f};
  float mrow[4] = {-3e38f,-3e38f,-3e38f,-3e38f};
  float lrow[4] = {0.f,0.f,0.f,0.f};

  for (int kv = 0; kv <= kvmax; ++kv) {
    int kvb = kv * 64;
    f32x4 sc[4];
    __builtin_amdgcn_s_setprio(1);
#pragma unroll
    for (int ct = 0; ct < 4; ++ct) {
      f32x4 s4 = (f32x4){0.f,0.f,0.f,0.f};
#pragma unroll
      for (int kc = 0; kc < 4; ++kc) {
        bf16x8 kf = *(const bf16x8*)(Kp + (size_t)(kvb + ct*16 + l15)*HD_ + kc*32 + l4*8);
        s4 = __builtin_amdgcn_mfma_f32_16x16x32_bf16(qf[kc], kf, s4, 0, 0, 0);
      }
      sc[ct] = s4;
    }
    __builtin_amdgcn_s_setprio(0);
    if (kv == kvmax) {
#pragma unroll
      for (int ct = 0; ct < 4; ++ct)
#pragma unroll
        for (int r = 0; r < 4; ++r) {
          int col = kvb + ct*16 + l15;
          int rw  = qrow0 + l4*4 + r;
          if (col > rw) sc[ct][r] = -1e9f;
        }
    }
    float f[4];
#pragma unroll
    for (int r = 0; r < 4; ++r) {
      float mx = fmaxf(fmaxf(sc[0][r], sc[1][r]), fmaxf(sc[2][r], sc[3][r]));
      mx = fmaxf(mx, __shfl_xor(mx, 1));
      mx = fmaxf(mx, __shfl_xor(mx, 2));
      mx = fmaxf(mx, __shfl_xor(mx, 4));
      mx = fmaxf(mx, __shfl_xor(mx, 8));
      float nm = fmaxf(mrow[r], mx);
      f[r] = __expf(mrow[r] - nm);
      mrow[r] = nm;
    }
    float rs[4] = {0.f,0.f,0.f,0.f};
#pragma unroll
    for (int ct = 0; ct < 4; ++ct)
#pragma unroll
      for (int r = 0; r < 4; ++r) {
        float p = __expf(sc[ct][r] - mrow[r]);
        rs[r] += p;
        int row = l4*4 + r, col = ct*16 + l15;
        int byte = row*128 + (((col >> 3) ^ (row & 7)) << 4) + (col & 7)*2;
        *(u16*)(Pw + byte) = f2bf(p);
      }
#pragma unroll
    for (int r = 0; r < 4; ++r) {
      float sum = rs[r];
      sum += __shfl_xor(sum, 1);
      sum += __shfl_xor(sum, 2);
      sum += __shfl_xor(sum, 4);
      sum += __shfl_xor(sum, 8);
      lrow[r] = lrow[r]*f[r] + sum;
    }
#pragma unroll
    for (int n = 0; n < 8; ++n)
#pragma unroll
      for (int r = 0; r < 4; ++r) o[n][r] *= f[r];
    // P is same-wave private: compiler inserts lgkmcnt for the ds deps.
    __builtin_amdgcn_s_setprio(1);
#pragma unroll
    for (int kk = 0; kk < 2; ++kk) {
      int prow = l15, pslot = kk*4 + l4;
      bf16x8 pf = *(const bf16x8*)(Pw + prow*128 + ((pslot ^ (prow & 7)) << 4));
#pragma unroll
      for (int n = 0; n < 8; ++n) {
        bf16x8 vf = *(const bf16x8*)(Vp + (size_t)(n*16 + l15)*S_ + kvb + kk*32 + l4*8);
        o[n] = __builtin_amdgcn_mfma_f32_16x16x32_bf16(pf, vf, o[n], 0, 0, 0);
      }
    }
    __builtin_amdgcn_s_setprio(0);
  }
#pragma unroll
  for (int n = 0; n < 8; ++n)
#pragma unroll
    for (int r = 0; r < 4; ++r) {
      int srow = qrow0 + l4*4 + r;
      AOh[(size_t)srow * (H_*HD_) + n*16 + l15] = f2bf(o[n][r] / lrow[r]);
    }
}

// grid (16, H, B), block 128 = 2 independent waves; wave -> pair {c, 63-c}.
__global__ __launch_bounds__(128) void k_attn(
    const u16* __restrict__ Q, const u16* __restrict__ Kc,
    const u16* __restrict__ Vt, u16* __restrict__ AO)
{
  int w = threadIdx.x >> 6, lane = threadIdx.x & 63;
  int pairIdx = blockIdx.x * 2 + w;           // 0..31
  int h = blockIdx.y, b = blockIdx.z, g = h >> 2;
  const u16* Qh = Q  + ((size_t)b*H_   + h) * S_ * HD_;
  const u16* Kp = Kc + ((size_t)b*KVH_ + g) * S_ * HD_;
  const u16* Vp = Vt + ((size_t)b*KVH_ + g) * (size_t)HD_ * S_;   // [HD][S]
  u16* AOh = AO + ((size_t)b*S_) * (H_*HD_) + h*HD_;
  __shared__ u16 Pl[2][1024];
  char* Pw = (char*)&Pl[w][0];

  attn_chunk(pairIdx,      Qh, Kp, Vp, AOh, lane, Pw);
  attn_chunk(63 - pairIdx, Qh, Kp, Vp, AOh, lane, Pw);
}

extern "C" void kernel_launch(void* const* d_in, const int* in_sizes, int n_in,
                              void* d_out, int out_size, void* d_ws, size_t ws_size,
                              hipStream_t stream) {
  (void)in_sizes; (void)n_in; (void)out_size; (void)ws_size;
  const float* x   = (const float*)d_in[0];
  const int*   sid = (const int*)  d_in[1];
  // d_in[2] = cache (dead), d_in[3] = mask (dead: causal re-derived)
  const float* Wq  = (const float*)d_in[4];
  const float* bq  = (const float*)d_in[5];
  const float* Wk  = (const float*)d_in[6];
  const float* bk  = (const float*)d_in[7];
  const float* Wv  = (const float*)d_in[8];
  const float* bv  = (const float*)d_in[9];
  const float* Wo  = (const float*)d_in[10];
  float* out = (float*)d_out;

  char* ws = (char*)d_ws;
  u16*   xb   = (u16*)  (ws);                    // 16 MB (aliased by AO later)
  u16*   WB   = (u16*)  (ws + 16777216);         // 48 MB  [6144][4096]
  u16*   WoT  = (u16*)  (ws + 67108864);         // 32 MB  [4096][4096]
  float* Cq   = (float*)(ws + 100663296);        // 48 MB  [2048][6144]
  u16*   qb   = (u16*)  (ws + 150994944);        // 16 MB  [B][H][S][HD]
  u16*   kb   = (u16*)  (ws + 167772160);        //  4 MB  [B][KVH][S][HD]
  u16*   vb   = (u16*)  (ws + 171966464);        //  4 MB
  u16*   VT   = (u16*)  (ws + 176160768);        //  4 MB  [B][KVH][HD][S]
  float* cosd = (float*)(ws + 180355072);        // 256 KB
  float* sind = (float*)(ws + 180617216);        // 256 KB (total ~181 MB)
  u16*   AO   = xb;                              // attention output reuses xb

  dim3 tb(32, 8);
  k_convert<<<8192, 256, 0, stream>>>(x, xb, (2048*4096)/4);
  k_transpose_w<<<dim3(128,128), tb, 0, stream>>>(Wq, WB, 4096, 4096);
  k_transpose_w<<<dim3( 32,128), tb, 0, stream>>>(Wk, WB + (size_t)4096*4096, 4096, 1024);
  k_transpose_w<<<dim3( 32,128), tb, 0, stream>>>(Wv, WB + (size_t)5120*4096, 4096, 1024);
  k_transpose_w<<<dim3(128,128), tb, 0, stream>>>(Wo, WoT, 4096, 4096);
  k_rope<<<256, 256, 0, stream>>>(sid, cosd, sind);
  k_gemm<<<dim3(48,16), 256, 0, stream>>>(xb, WB, Cq, 2048, NQKV, 4096);
  k_pack<<<2048, 256, 0, stream>>>(Cq, bq, bk, bv, cosd, sind, qb, kb, vb);
  k_transpose_v<<<dim3(32,4,16), tb, 0, stream>>>(vb, VT);
  k_attn<<<dim3(16,32,2), 128, 0, stream>>>(qb, kb, VT, AO);
  k_gemm<<<dim3(32,16), 256, 0, stream>>>(AO, WoT, out, 2048, 4096, 4096);
}

// Round 6
// 435.885 us; speedup vs baseline: 2.0442x; 1.0841x over previous
//
#include <hip/hip_runtime.h>
#include <hip/hip_bf16.h>

typedef unsigned short u16;
typedef unsigned int   u32;
using bf16x8 = __attribute__((ext_vector_type(8))) short;
using f32x4  = __attribute__((ext_vector_type(4))) float;

#define AS1 __attribute__((address_space(1)))
#define AS3 __attribute__((address_space(3)))

static constexpr int S_   = 1024;
static constexpr int D_   = 4096;
static constexpr int H_   = 32;
static constexpr int KVH_ = 8;
static constexpr int HD_  = 128;
static constexpr int NQKV = H_*HD_ + 2*KVH_*HD_;   // 6144

__device__ __forceinline__ u16 f2bf(float f) {
  union { float f; u32 u; } v; v.f = f;
  u32 r = v.u + 0x7FFFu + ((v.u >> 16) & 1u);      // RTNE
  return (u16)(r >> 16);
}

// ---------------- x f32 -> bf16 ----------------
__global__ void k_convert(const float* __restrict__ src, u16* __restrict__ dst, int n4) {
  int i = blockIdx.x * blockDim.x + threadIdx.x;
  if (i >= n4) return;
  float4 v = ((const float4*)src)[i];
  ushort4 o;
  o.x = f2bf(v.x); o.y = f2bf(v.y); o.z = f2bf(v.z); o.w = f2bf(v.w);
  ((ushort4*)dst)[i] = o;
}

// ---------------- W [K][N] f32 -> Wt [N][K] bf16 ----------------
__global__ void k_transpose_w(const float* __restrict__ src, u16* __restrict__ dst,
                              int K, int N) {
  __shared__ float t[32][33];
  int k0 = blockIdx.y * 32, n0 = blockIdx.x * 32;
  int tx = threadIdx.x, ty = threadIdx.y;           // (32,8)
#pragma unroll
  for (int i = 0; i < 4; ++i)
    t[ty + i*8][tx] = src[(size_t)(k0 + ty + i*8) * N + n0 + tx];
  __syncthreads();
#pragma unroll
  for (int i = 0; i < 4; ++i)
    dst[(size_t)(n0 + ty + i*8) * K + k0 + tx] = f2bf(t[tx][ty + i*8]);
}

// ---------------- V [BG][S][HD] bf16 -> Vt [BG][HD][S] bf16 ----------------
__global__ void k_transpose_v(const u16* __restrict__ src, u16* __restrict__ dst) {
  __shared__ u16 t[32][33];
  int bg = blockIdx.z;
  int s0 = blockIdx.x * 32, h0 = blockIdx.y * 32;
  src += (size_t)bg * S_ * HD_;
  dst += (size_t)bg * S_ * HD_;
  int tx = threadIdx.x, ty = threadIdx.y;
#pragma unroll
  for (int i = 0; i < 4; ++i)
    t[ty + i*8][tx] = src[(size_t)(s0 + ty + i*8) * HD_ + h0 + tx];
  __syncthreads();
#pragma unroll
  for (int i = 0; i < 4; ++i)
    dst[(size_t)(h0 + ty + i*8) * S_ + s0 + tx] = t[tx][ty + i*8];
}

// ---------------- RoPE tables: cos/sin [S][64] f32 ----------------
__global__ void k_rope(const int* __restrict__ sidx, float* __restrict__ cosd,
                       float* __restrict__ sind) {
  int i = blockIdx.x * blockDim.x + threadIdx.x;    // S*64
  int s = i >> 6, d = i & 63;
  float pos  = (float)sidx[s];
  float invf = expf(-0.21586735246819178f * (float)d);  // 1e6^(-d/64)
  float ph   = pos * invf;
  cosd[i] = cosf(ph);
  sind[i] = sinf(ph);
}

// ---- 256xBN bf16 GEMM, counted-vmcnt double-buffered pipeline ----
// C[M][N] = A[M][K] * Bt[N][K]^T. 512 thr = 8 waves (2M x 4N), BK=64.
// Per K-tile: 4 quadrant phases (16 MFMA each) -> s_barrier ->
// stage kt+2 into the just-freed buffer -> s_waitcnt vmcnt(LOADS) [kt+1
// landed; kt+2's LOADS remain in flight] -> s_barrier. Never drains to 0.
template<int BN>
__global__ __launch_bounds__(512, 2) void k_gemm2(
    const u16* __restrict__ A, const u16* __restrict__ Bt,
    float* __restrict__ C, int N, int K)
{
  constexpr int WN   = BN / 4;          // wave cols: 64 or 32
  constexpr int NJ   = WN / 16;         // B frags per wave: 4 or 2
  constexpr int BCH  = BN / 64;         // B stage chunks: 4 or 2
  constexpr int ABYT = 256 * 128;       // 32 KB per A tile
  constexpr int BBYT = BN * 128;        // 32/16 KB per B tile
  __shared__ char lds[2 * (ABYT + BBYT)];

  // XCD-bijective swizzle (gridDim.x % 8 == 0 guaranteed by launch shapes)
  int cpx = gridDim.x >> 3;
  int wkid = ((int)blockIdx.x & 7) * cpx + ((int)blockIdx.x >> 3);
  int NT = N / BN;
  int m0 = (wkid / NT) * 256, n0 = (wkid % NT) * BN;

  int tid = threadIdx.x, w = tid >> 6, lane = tid & 63;
  int l15 = lane & 15, l4 = lane >> 4;
  int wr = w >> 2, wc = w & 3;          // 2 x 4 wave grid
  int row0 = tid >> 3;                  // staging row within 64-row chunk
  int ss   = (tid & 7) ^ (row0 & 7);    // pre-swizzled source slot

  f32x4 acc[8][NJ];
#pragma unroll
  for (int i = 0; i < 8; ++i)
#pragma unroll
    for (int j = 0; j < NJ; ++j) acc[i][j] = (f32x4){0.f,0.f,0.f,0.f};

#define STAGE(kt_) {                                                         \
    char* lb = lds + ((kt_) & 1) * (ABYT + BBYT);                            \
    const u16* ag = A  + (size_t)(m0 + row0) * K + (kt_)*64 + ss*8;          \
    const u16* bg = Bt + (size_t)(n0 + row0) * K + (kt_)*64 + ss*8;          \
    _Pragma("unroll")                                                        \
    for (int c = 0; c < 4; ++c)                                              \
      __builtin_amdgcn_global_load_lds((AS1 void*)(ag + (size_t)c*64*K),     \
          (AS3 void*)(lb + c*8192 + w*1024), 16, 0, 0);                      \
    _Pragma("unroll")                                                        \
    for (int c = 0; c < BCH; ++c)                                            \
      __builtin_amdgcn_global_load_lds((AS1 void*)(bg + (size_t)c*64*K),     \
          (AS3 void*)(lb + ABYT + c*8192 + w*1024), 16, 0, 0);               \
  }

  STAGE(0);
  STAGE(1);
  if constexpr (BN == 256) asm volatile("s_waitcnt vmcnt(8)" ::: "memory");
  else                     asm volatile("s_waitcnt vmcnt(6)" ::: "memory");
  __builtin_amdgcn_s_barrier();
  __builtin_amdgcn_sched_barrier(0);

  int NK = K >> 6;
  for (int kt = 0; kt < NK; ++kt) {
    char* lA = lds + (kt & 1) * (ABYT + BBYT);
    char* lB = lA + ABYT;
#pragma unroll
    for (int qm = 0; qm < 2; ++qm) {
      bf16x8 af[4][2];
#pragma unroll
      for (int i = 0; i < 4; ++i)
#pragma unroll
        for (int kk = 0; kk < 2; ++kk) {
          int row = wr*128 + (qm*4 + i)*16 + l15;
          int ks = kk*4 + l4;
          af[i][kk] = *(const bf16x8*)(lA + row*128 + ((ks ^ (row & 7)) << 4));
        }
#pragma unroll
      for (int qn = 0; qn < NJ/2; ++qn) {
        bf16x8 bfv[2][2];
#pragma unroll
        for (int j2 = 0; j2 < 2; ++j2)
#pragma unroll
          for (int kk = 0; kk < 2; ++kk) {
            int row = wc*WN + (qn*2 + j2)*16 + l15;
            int ks = kk*4 + l4;
            bfv[j2][kk] = *(const bf16x8*)(lB + row*128 + ((ks ^ (row & 7)) << 4));
          }
        __builtin_amdgcn_s_setprio(1);
#pragma unroll
        for (int i = 0; i < 4; ++i)
#pragma unroll
          for (int j2 = 0; j2 < 2; ++j2)
#pragma unroll
            for (int kk = 0; kk < 2; ++kk)
              acc[qm*4 + i][qn*2 + j2] = __builtin_amdgcn_mfma_f32_16x16x32_bf16(
                  af[i][kk], bfv[j2][kk], acc[qm*4 + i][qn*2 + j2], 0, 0, 0);
        __builtin_amdgcn_s_setprio(0);
      }
    }
    __builtin_amdgcn_s_barrier();        // all waves done reading buf kt&1
    __builtin_amdgcn_sched_barrier(0);
    if (kt + 2 < NK) {
      STAGE(kt + 2);                     // into buf kt&1 (now dead)
      if constexpr (BN == 256) asm volatile("s_waitcnt vmcnt(8)" ::: "memory");
      else                     asm volatile("s_waitcnt vmcnt(6)" ::: "memory");
    } else {
      asm volatile("s_waitcnt vmcnt(0)" ::: "memory");
    }
    __builtin_amdgcn_s_barrier();        // everyone's kt+1 loads landed
    __builtin_amdgcn_sched_barrier(0);
  }
#undef STAGE

#pragma unroll
  for (int i = 0; i < 8; ++i)
#pragma unroll
    for (int j = 0; j < NJ; ++j) {
      int r0 = m0 + wr*128 + i*16 + l4*4;
      int c0 = n0 + wc*WN + j*16 + l15;
#pragma unroll
      for (int r = 0; r < 4; ++r)
        C[(size_t)(r0 + r) * N + c0] = acc[i][j][r];
    }
}

// ---------------- bias + RoPE + pack to [B][H][S][HD] bf16 ----------------
__global__ void k_pack(const float* __restrict__ Cq,
                       const float* __restrict__ bq, const float* __restrict__ bk,
                       const float* __restrict__ bv,
                       const float* __restrict__ cosd, const float* __restrict__ sind,
                       u16* __restrict__ qb, u16* __restrict__ kb, u16* __restrict__ vb) {
  int t = blockIdx.x;
  int b = t >> 10, s = t & 1023;
  const float* row = Cq + (size_t)t * NQKV;
  const float* cs = cosd + s*64;
  const float* sn = sind + s*64;
  const float qscale = 0.08838834764831845f;  // 1/sqrt(HD)
  for (int c = threadIdx.x; c < H_*HD_; c += blockDim.x) {
    int h = c >> 7, d = c & 127;
    float v = row[c] + bq[c];
    float o;
    if (d < 64) { float p = row[c + 64] + bq[c + 64]; o = v*cs[d]    - p*sn[d]; }
    else        { float p = row[c - 64] + bq[c - 64]; o = v*cs[d-64] + p*sn[d-64]; }
    qb[(((size_t)b*H_ + h)*S_ + s)*HD_ + d] = f2bf(o * qscale);
  }
  for (int c = threadIdx.x; c < KVH_*HD_; c += blockDim.x) {
    int g = c >> 7, d = c & 127;
    float v = row[H_*HD_ + c] + bk[c];
    float o;
    if (d < 64) { float p = row[H_*HD_ + c + 64] + bk[c + 64]; o = v*cs[d]    - p*sn[d]; }
    else        { float p = row[H_*HD_ + c - 64] + bk[c - 64]; o = v*cs[d-64] + p*sn[d-64]; }
    size_t idx = (((size_t)b*KVH_ + g)*S_ + s)*HD_ + d;
    kb[idx] = f2bf(o);
    vb[idx] = f2bf(row[H_*HD_ + KVH_*HD_ + c] + bv[c]);
  }
}

// ---------------- causal GQA flash attention (wave-independent 16-row chunks) --------
__device__ __forceinline__ void attn_chunk(
    int chunk, const u16* __restrict__ Qh, const u16* __restrict__ Kp,
    const u16* __restrict__ Vp, u16* __restrict__ AOh, int lane, char* Pw)
{
  int l15 = lane & 15, l4 = lane >> 4;
  int qrow0 = chunk * 16;
  int kvmax = chunk >> 2;

  bf16x8 qf[4];
#pragma unroll
  for (int kc = 0; kc < 4; ++kc)
    qf[kc] = *(const bf16x8*)(Qh + (size_t)(qrow0 + l15)*HD_ + kc*32 + l4*8);

  f32x4 o[8];
#pragma unroll
  for (int n = 0; n < 8; ++n) o[n] = (f32x4){0.f,0.f,0.f,0.f};
  float mrow[4] = {-3e38f,-3e38f,-3e38f,-3e38f};
  float lrow[4] = {0.f,0.f,0.f,0.f};

  for (int kv = 0; kv <= kvmax; ++kv) {
    int kvb = kv * 64;
    f32x4 sc[4];
    __builtin_amdgcn_s_setprio(1);
#pragma unroll
    for (int ct = 0; ct < 4; ++ct) {
      f32x4 s4 = (f32x4){0.f,0.f,0.f,0.f};
#pragma unroll
      for (int kc = 0; kc < 4; ++kc) {
        bf16x8 kf = *(const bf16x8*)(Kp + (size_t)(kvb + ct*16 + l15)*HD_ + kc*32 + l4*8);
        s4 = __builtin_amdgcn_mfma_f32_16x16x32_bf16(qf[kc], kf, s4, 0, 0, 0);
      }
      sc[ct] = s4;
    }
    __builtin_amdgcn_s_setprio(0);
    if (kv == kvmax) {
#pragma unroll
      for (int ct = 0; ct < 4; ++ct)
#pragma unroll
        for (int r = 0; r < 4; ++r) {
          int col = kvb + ct*16 + l15;
          int rw  = qrow0 + l4*4 + r;
          if (col > rw) sc[ct][r] = -1e9f;
        }
    }
    float f[4];
#pragma unroll
    for (int r = 0; r < 4; ++r) {
      float mx = fmaxf(fmaxf(sc[0][r], sc[1][r]), fmaxf(sc[2][r], sc[3][r]));
      mx = fmaxf(mx, __shfl_xor(mx, 1));
      mx = fmaxf(mx, __shfl_xor(mx, 2));
      mx = fmaxf(mx, __shfl_xor(mx, 4));
      mx = fmaxf(mx, __shfl_xor(mx, 8));
      float nm = fmaxf(mrow[r], mx);
      f[r] = __expf(mrow[r] - nm);
      mrow[r] = nm;
    }
    float rs[4] = {0.f,0.f,0.f,0.f};
#pragma unroll
    for (int ct = 0; ct < 4; ++ct)
#pragma unroll
      for (int r = 0; r < 4; ++r) {
        float p = __expf(sc[ct][r] - mrow[r]);
        rs[r] += p;
        int row = l4*4 + r, col = ct*16 + l15;
        int byte = row*128 + (((col >> 3) ^ (row & 7)) << 4) + (col & 7)*2;
        *(u16*)(Pw + byte) = f2bf(p);
      }
#pragma unroll
    for (int r = 0; r < 4; ++r) {
      float sum = rs[r];
      sum += __shfl_xor(sum, 1);
      sum += __shfl_xor(sum, 2);
      sum += __shfl_xor(sum, 4);
      sum += __shfl_xor(sum, 8);
      lrow[r] = lrow[r]*f[r] + sum;
    }
#pragma unroll
    for (int n = 0; n < 8; ++n)
#pragma unroll
      for (int r = 0; r < 4; ++r) o[n][r] *= f[r];
    __builtin_amdgcn_s_setprio(1);
#pragma unroll
    for (int kk = 0; kk < 2; ++kk) {
      int prow = l15, pslot = kk*4 + l4;
      bf16x8 pf = *(const bf16x8*)(Pw + prow*128 + ((pslot ^ (prow & 7)) << 4));
#pragma unroll
      for (int n = 0; n < 8; ++n) {
        bf16x8 vf = *(const bf16x8*)(Vp + (size_t)(n*16 + l15)*S_ + kvb + kk*32 + l4*8);
        o[n] = __builtin_amdgcn_mfma_f32_16x16x32_bf16(pf, vf, o[n], 0, 0, 0);
      }
    }
    __builtin_amdgcn_s_setprio(0);
  }
#pragma unroll
  for (int n = 0; n < 8; ++n)
#pragma unroll
    for (int r = 0; r < 4; ++r) {
      int srow = qrow0 + l4*4 + r;
      AOh[(size_t)srow * (H_*HD_) + n*16 + l15] = f2bf(o[n][r] / lrow[r]);
    }
}

__global__ __launch_bounds__(128) void k_attn(
    const u16* __restrict__ Q, const u16* __restrict__ Kc,
    const u16* __restrict__ Vt, u16* __restrict__ AO)
{
  int w = threadIdx.x >> 6, lane = threadIdx.x & 63;
  int pairIdx = blockIdx.x * 2 + w;           // 0..31
  int h = blockIdx.y, b = blockIdx.z, g = h >> 2;
  const u16* Qh = Q  + ((size_t)b*H_   + h) * S_ * HD_;
  const u16* Kp = Kc + ((size_t)b*KVH_ + g) * S_ * HD_;
  const u16* Vp = Vt + ((size_t)b*KVH_ + g) * (size_t)HD_ * S_;   // [HD][S]
  u16* AOh = AO + ((size_t)b*S_) * (H_*HD_) + h*HD_;
  __shared__ u16 Pl[2][1024];
  char* Pw = (char*)&Pl[w][0];

  attn_chunk(pairIdx,      Qh, Kp, Vp, AOh, lane, Pw);
  attn_chunk(63 - pairIdx, Qh, Kp, Vp, AOh, lane, Pw);
}

extern "C" void kernel_launch(void* const* d_in, const int* in_sizes, int n_in,
                              void* d_out, int out_size, void* d_ws, size_t ws_size,
                              hipStream_t stream) {
  (void)in_sizes; (void)n_in; (void)out_size; (void)ws_size;
  const float* x   = (const float*)d_in[0];
  const int*   sid = (const int*)  d_in[1];
  // d_in[2] = cache (dead), d_in[3] = mask (dead: causal re-derived)
  const float* Wq  = (const float*)d_in[4];
  const float* bq  = (const float*)d_in[5];
  const float* Wk  = (const float*)d_in[6];
  const float* bk  = (const float*)d_in[7];
  const float* Wv  = (const float*)d_in[8];
  const float* bv  = (const float*)d_in[9];
  const float* Wo  = (const float*)d_in[10];
  float* out = (float*)d_out;

  char* ws = (char*)d_ws;
  u16*   xb   = (u16*)  (ws);                    // 16 MB (aliased by AO later)
  u16*   WB   = (u16*)  (ws + 16777216);         // 48 MB  [6144][4096]
  u16*   WoT  = (u16*)  (ws + 67108864);         // 32 MB  [4096][4096]
  float* Cq   = (float*)(ws + 100663296);        // 48 MB  [2048][6144]
  u16*   qb   = (u16*)  (ws + 150994944);        // 16 MB  [B][H][S][HD]
  u16*   kb   = (u16*)  (ws + 167772160);        //  4 MB  [B][KVH][S][HD]
  u16*   vb   = (u16*)  (ws + 171966464);        //  4 MB
  u16*   VT   = (u16*)  (ws + 176160768);        //  4 MB  [B][KVH][HD][S]
  float* cosd = (float*)(ws + 180355072);        // 256 KB
  float* sind = (float*)(ws + 180617216);        // 256 KB (total ~181 MB)
  u16*   AO   = xb;                              // attention output reuses xb

  dim3 tb(32, 8);
  k_convert<<<8192, 256, 0, stream>>>(x, xb, (2048*4096)/4);
  k_transpose_w<<<dim3(128,128), tb, 0, stream>>>(Wq, WB, 4096, 4096);
  k_transpose_w<<<dim3( 32,128), tb, 0, stream>>>(Wk, WB + (size_t)4096*4096, 4096, 1024);
  k_transpose_w<<<dim3( 32,128), tb, 0, stream>>>(Wv, WB + (size_t)5120*4096, 4096, 1024);
  k_transpose_w<<<dim3(128,128), tb, 0, stream>>>(Wo, WoT, 4096, 4096);
  k_rope<<<256, 256, 0, stream>>>(sid, cosd, sind);
  k_gemm2<256><<<192, 512, 0, stream>>>(xb, WB, Cq, NQKV, 4096);
  k_pack<<<2048, 256, 0, stream>>>(Cq, bq, bk, bv, cosd, sind, qb, kb, vb);
  k_transpose_v<<<dim3(32,4,16), tb, 0, stream>>>(vb, VT);
  k_attn<<<dim3(16,32,2), 128, 0, stream>>>(qb, kb, VT, AO);
  k_gemm2<128><<<256, 512, 0, stream>>>(AO, WoT, out, 4096, 4096);
}

// Round 7
// 416.642 us; speedup vs baseline: 2.1387x; 1.0462x over previous
//
#include <hip/hip_runtime.h>
#include <hip/hip_bf16.h>

typedef unsigned short u16;
typedef unsigned int   u32;
using bf16x8 = __attribute__((ext_vector_type(8))) short;
using f32x4  = __attribute__((ext_vector_type(4))) float;

#define AS1 __attribute__((address_space(1)))
#define AS3 __attribute__((address_space(3)))

static constexpr int S_   = 1024;
static constexpr int D_   = 4096;
static constexpr int H_   = 32;
static constexpr int KVH_ = 8;
static constexpr int HD_  = 128;
static constexpr int NQKV = H_*HD_ + 2*KVH_*HD_;   // 6144

__device__ __forceinline__ u16 f2bf(float f) {
  union { float f; u32 u; } v; v.f = f;
  u32 r = v.u + 0x7FFFu + ((v.u >> 16) & 1u);      // RTNE
  return (u16)(r >> 16);
}

// ---------------- x f32 -> bf16 ----------------
__global__ void k_convert(const float* __restrict__ src, u16* __restrict__ dst, int n4) {
  int i = blockIdx.x * blockDim.x + threadIdx.x;
  if (i >= n4) return;
  float4 v = ((const float4*)src)[i];
  ushort4 o;
  o.x = f2bf(v.x); o.y = f2bf(v.y); o.z = f2bf(v.z); o.w = f2bf(v.w);
  ((ushort4*)dst)[i] = o;
}

// ---------------- W [K][N] f32 -> Wt [N][K] bf16 ----------------
__global__ void k_transpose_w(const float* __restrict__ src, u16* __restrict__ dst,
                              int K, int N) {
  __shared__ float t[32][33];
  int k0 = blockIdx.y * 32, n0 = blockIdx.x * 32;
  int tx = threadIdx.x, ty = threadIdx.y;           // (32,8)
#pragma unroll
  for (int i = 0; i < 4; ++i)
    t[ty + i*8][tx] = src[(size_t)(k0 + ty + i*8) * N + n0 + tx];
  __syncthreads();
#pragma unroll
  for (int i = 0; i < 4; ++i)
    dst[(size_t)(n0 + ty + i*8) * K + k0 + tx] = f2bf(t[tx][ty + i*8]);
}

// ---------------- V [BG][S][HD] bf16 -> Vt [BG][HD][S] bf16 ----------------
__global__ void k_transpose_v(const u16* __restrict__ src, u16* __restrict__ dst) {
  __shared__ u16 t[32][33];
  int bg = blockIdx.z;
  int s0 = blockIdx.x * 32, h0 = blockIdx.y * 32;
  src += (size_t)bg * S_ * HD_;
  dst += (size_t)bg * S_ * HD_;
  int tx = threadIdx.x, ty = threadIdx.y;
#pragma unroll
  for (int i = 0; i < 4; ++i)
    t[ty + i*8][tx] = src[(size_t)(s0 + ty + i*8) * HD_ + h0 + tx];
  __syncthreads();
#pragma unroll
  for (int i = 0; i < 4; ++i)
    dst[(size_t)(h0 + ty + i*8) * S_ + s0 + tx] = t[tx][ty + i*8];
}

// ---------------- RoPE tables: cos/sin [S][64] f32 ----------------
__global__ void k_rope(const int* __restrict__ sidx, float* __restrict__ cosd,
                       float* __restrict__ sind) {
  int i = blockIdx.x * blockDim.x + threadIdx.x;    // S*64
  int s = i >> 6, d = i & 63;
  float pos  = (float)sidx[s];
  float invf = expf(-0.21586735246819178f * (float)d);  // 1e6^(-d/64)
  float ph   = pos * invf;
  cosd[i] = cosf(ph);
  sind[i] = sinf(ph);
}

// ---- 256xBN bf16 GEMM, 8-phase counted-vmcnt pipeline (m201-style, plain HIP) ----
// C[M][N] = A[M][K] * Bt[N][K]^T. 512 thr = 8 waves (2M x 4N), BK=64.
// Per K-tile: 4 sub-phases, each {ds_read subtile || stage chunks -> s_barrier ->
// lgkmcnt(0) -> setprio+16 MFMA -> s_barrier}. Chunk-rotation staging:
//   ph0: A[*][hi](kt+1)   ph1: B(kt+1)   ph2: A[*][lo](kt+2)   ph3: vmcnt(2)
// (A lo-chunks of buf kt&1 are dead after ph1 -> host kt+2's prefetch.)
// vmcnt never drains to 0 in steady state.
template<int BN>
__global__ __launch_bounds__(512, 2) void k_gemm3(
    const u16* __restrict__ A, const u16* __restrict__ Bt,
    float* __restrict__ C, int N, int K)
{
  constexpr int WN = BN/4, NJ = WN/16, NH = NJ/2;   // BN256: 64/4/2, BN128: 32/2/1
  constexpr int ABYT = 256*128, BBYT = BN*128, STEP = ABYT+BBYT;
  __shared__ __align__(16) char lds[2*STEP];

  const int cpx = (int)gridDim.x >> 3;
  const int wkid = ((int)blockIdx.x & 7)*cpx + ((int)blockIdx.x >> 3);
  const int NT = N / BN;
  const int m0 = (wkid / NT) * 256, n0 = (wkid % NT) * BN;
  const int tid = threadIdx.x, w = tid>>6, lane = tid&63;
  const int l15 = lane&15, l4 = lane>>4;
  const int wr = w>>2, wc = w&3;
  const int row0 = tid>>3;                 // staging row in 64-row chunk
  const int ss = (tid&7) ^ (row0&7);       // pre-swizzled source slot
  const int NK = K >> 6;

  f32x4 acc[8][NJ];
#pragma unroll
  for (int i = 0; i < 8; ++i)
#pragma unroll
    for (int j = 0; j < NJ; ++j) acc[i][j] = (f32x4){0.f,0.f,0.f,0.f};

  bf16x8 af[4][2];
  bf16x8 bf[2][NH][2];

  // stage one 64-row chunk (8KB): part 0=A,1=B; rows [r0c, r0c+64)
#define CHUNK(kt_, part_, r0c_)                                               \
  __builtin_amdgcn_global_load_lds(                                           \
    (AS1 void*)(((part_) ? Bt + (size_t)(n0 + (r0c_) + row0)*K                \
                         : A  + (size_t)(m0 + (r0c_) + row0)*K)               \
                + (size_t)(kt_)*64 + ss*8),                                   \
    (AS3 void*)(lds + ((kt_)&1)*STEP + (part_)*ABYT + (r0c_)*128 + w*1024),   \
    16, 0, 0)

#define LOAD_A(mh_)                                                           \
  _Pragma("unroll") for (int i = 0; i < 4; ++i)                               \
  _Pragma("unroll") for (int kk = 0; kk < 2; ++kk) {                          \
    int row = wr*128 + (mh_)*64 + i*16 + l15;                                 \
    af[i][kk] = *(const bf16x8*)(lA + row*128 + (((kk*4+l4) ^ (row&7)) << 4)); }

#define LOAD_B(nh_)                                                           \
  _Pragma("unroll") for (int jj = 0; jj < NH; ++jj)                           \
  _Pragma("unroll") for (int kk = 0; kk < 2; ++kk) {                          \
    int row = wc*WN + ((nh_)*NH + jj)*16 + l15;                               \
    bf[nh_][jj][kk] = *(const bf16x8*)(lB + row*128 + (((kk*4+l4) ^ (row&7)) << 4)); }

#define MFMA_PH(mh_, nh_)                                                     \
  __builtin_amdgcn_s_setprio(1);                                              \
  _Pragma("unroll") for (int i = 0; i < 4; ++i)                               \
  _Pragma("unroll") for (int jj = 0; jj < NH; ++jj)                           \
  _Pragma("unroll") for (int kk = 0; kk < 2; ++kk)                            \
    acc[(mh_)*4+i][(nh_)*NH+jj] = __builtin_amdgcn_mfma_f32_16x16x32_bf16(    \
        af[i][kk], bf[nh_][jj][kk], acc[(mh_)*4+i][(nh_)*NH+jj], 0, 0, 0);    \
  __builtin_amdgcn_s_setprio(0);

#define BAR   __builtin_amdgcn_s_barrier()
#define SCHB  __builtin_amdgcn_sched_barrier(0)
#define WLGKM asm volatile("s_waitcnt lgkmcnt(0)" ::: "memory")

  // ---- prologue: tile0 full + tile1's early chunks; counted wait ----
  CHUNK(0,0,0); CHUNK(0,0,64); CHUNK(0,0,128); CHUNK(0,0,192);
  CHUNK(0,1,0); CHUNK(0,1,64);
  if constexpr (BN == 256) { CHUNK(0,1,128); CHUNK(0,1,192); }
  CHUNK(1,0,0); CHUNK(1,0,128);
  asm volatile("s_waitcnt vmcnt(2)" ::: "memory");
  BAR; SCHB;

  for (int kt = 0; kt < NK; ++kt) {
    const char* lA = lds + (kt&1)*STEP;
    const char* lB = lA + ABYT;
    // ---- ph0: quadrant (0,0); stage A hi-chunks of kt+1 ----
    LOAD_A(0); LOAD_B(0);
    if (kt+1 < NK) { CHUNK(kt+1,0,64); CHUNK(kt+1,0,192); }
    BAR; WLGKM; SCHB;
    MFMA_PH(0,0);
    BAR;
    // ---- ph1: quadrant (0,1); stage B of kt+1 ----
    LOAD_B(1);
    if (kt+1 < NK) {
      CHUNK(kt+1,1,0); CHUNK(kt+1,1,64);
      if constexpr (BN == 256) { CHUNK(kt+1,1,128); CHUNK(kt+1,1,192); }
    }
    BAR; WLGKM; SCHB;
    MFMA_PH(0,1);
    BAR;
    // ---- ph2: quadrant (1,0); stage A lo-chunks of kt+2 (slots dead since ph1) ----
    LOAD_A(1);
    if (kt+2 < NK) { CHUNK(kt+2,0,0); CHUNK(kt+2,0,128); }
    BAR; WLGKM; SCHB;
    MFMA_PH(1,0);
    BAR;
    // ---- ph3: quadrant (1,1); counted tile-boundary wait ----
    if (kt+2 < NK) asm volatile("s_waitcnt vmcnt(2)" ::: "memory");
    else           asm volatile("s_waitcnt vmcnt(0)" ::: "memory");
    BAR; WLGKM; SCHB;
    MFMA_PH(1,1);
    BAR;
  }
#undef CHUNK
#undef LOAD_A
#undef LOAD_B
#undef MFMA_PH

#pragma unroll
  for (int i = 0; i < 8; ++i)
#pragma unroll
    for (int j = 0; j < NJ; ++j) {
      int r0 = m0 + wr*128 + i*16 + l4*4;
      int c0 = n0 + wc*WN + j*16 + l15;
#pragma unroll
      for (int r = 0; r < 4; ++r)
        C[(size_t)(r0 + r) * N + c0] = acc[i][j][r];
    }
}

// ---------------- bias + RoPE + pack to [B][H][S][HD] bf16 ----------------
__global__ void k_pack(const float* __restrict__ Cq,
                       const float* __restrict__ bq, const float* __restrict__ bk,
                       const float* __restrict__ bv,
                       const float* __restrict__ cosd, const float* __restrict__ sind,
                       u16* __restrict__ qb, u16* __restrict__ kb, u16* __restrict__ vb) {
  int t = blockIdx.x;
  int b = t >> 10, s = t & 1023;
  const float* row = Cq + (size_t)t * NQKV;
  const float* cs = cosd + s*64;
  const float* sn = sind + s*64;
  const float qscale = 0.08838834764831845f;  // 1/sqrt(HD)
  for (int c = threadIdx.x; c < H_*HD_; c += blockDim.x) {
    int h = c >> 7, d = c & 127;
    float v = row[c] + bq[c];
    float o;
    if (d < 64) { float p = row[c + 64] + bq[c + 64]; o = v*cs[d]    - p*sn[d]; }
    else        { float p = row[c - 64] + bq[c - 64]; o = v*cs[d-64] + p*sn[d-64]; }
    qb[(((size_t)b*H_ + h)*S_ + s)*HD_ + d] = f2bf(o * qscale);
  }
  for (int c = threadIdx.x; c < KVH_*HD_; c += blockDim.x) {
    int g = c >> 7, d = c & 127;
    float v = row[H_*HD_ + c] + bk[c];
    float o;
    if (d < 64) { float p = row[H_*HD_ + c + 64] + bk[c + 64]; o = v*cs[d]    - p*sn[d]; }
    else        { float p = row[H_*HD_ + c - 64] + bk[c - 64]; o = v*cs[d-64] + p*sn[d-64]; }
    size_t idx = (((size_t)b*KVH_ + g)*S_ + s)*HD_ + d;
    kb[idx] = f2bf(o);
    vb[idx] = f2bf(row[H_*HD_ + KVH_*HD_ + c] + bv[c]);
  }
}

// ---------------- causal GQA flash attention (wave-independent 16-row chunks) --------
__device__ __forceinline__ void attn_chunk(
    int chunk, const u16* __restrict__ Qh, const u16* __restrict__ Kp,
    const u16* __restrict__ Vp, u16* __restrict__ AOh, int lane, char* Pw)
{
  int l15 = lane & 15, l4 = lane >> 4;
  int qrow0 = chunk * 16;
  int kvmax = chunk >> 2;

  bf16x8 qf[4];
#pragma unroll
  for (int kc = 0; kc < 4; ++kc)
    qf[kc] = *(const bf16x8*)(Qh + (size_t)(qrow0 + l15)*HD_ + kc*32 + l4*8);

  f32x4 o[8];
#pragma unroll
  for (int n = 0; n < 8; ++n) o[n] = (f32x4){0.f,0.f,0.f,0.f};
  float mrow[4] = {-3e38f,-3e38f,-3e38f,-3e38f};
  float lrow[4] = {0.f,0.f,0.f,0.f};

  for (int kv = 0; kv <= kvmax; ++kv) {
    int kvb = kv * 64;
    f32x4 sc[4];
    __builtin_amdgcn_s_setprio(1);
#pragma unroll
    for (int ct = 0; ct < 4; ++ct) {
      f32x4 s4 = (f32x4){0.f,0.f,0.f,0.f};
#pragma unroll
      for (int kc = 0; kc < 4; ++kc) {
        bf16x8 kf = *(const bf16x8*)(Kp + (size_t)(kvb + ct*16 + l15)*HD_ + kc*32 + l4*8);
        s4 = __builtin_amdgcn_mfma_f32_16x16x32_bf16(qf[kc], kf, s4, 0, 0, 0);
      }
      sc[ct] = s4;
    }
    __builtin_amdgcn_s_setprio(0);
    if (kv == kvmax) {
#pragma unroll
      for (int ct = 0; ct < 4; ++ct)
#pragma unroll
        for (int r = 0; r < 4; ++r) {
          int col = kvb + ct*16 + l15;
          int rw  = qrow0 + l4*4 + r;
          if (col > rw) sc[ct][r] = -1e9f;
        }
    }
    float f[4];
#pragma unroll
    for (int r = 0; r < 4; ++r) {
      float mx = fmaxf(fmaxf(sc[0][r], sc[1][r]), fmaxf(sc[2][r], sc[3][r]));
      mx = fmaxf(mx, __shfl_xor(mx, 1));
      mx = fmaxf(mx, __shfl_xor(mx, 2));
      mx = fmaxf(mx, __shfl_xor(mx, 4));
      mx = fmaxf(mx, __shfl_xor(mx, 8));
      float nm = fmaxf(mrow[r], mx);
      f[r] = __expf(mrow[r] - nm);
      mrow[r] = nm;
    }
    float rs[4] = {0.f,0.f,0.f,0.f};
#pragma unroll
    for (int ct = 0; ct < 4; ++ct)
#pragma unroll
      for (int r = 0; r < 4; ++r) {
        float p = __expf(sc[ct][r] - mrow[r]);
        rs[r] += p;
        int row = l4*4 + r, col = ct*16 + l15;
        int byte = row*128 + (((col >> 3) ^ (row & 7)) << 4) + (col & 7)*2;
        *(u16*)(Pw + byte) = f2bf(p);
      }
#pragma unroll
    for (int r = 0; r < 4; ++r) {
      float sum = rs[r];
      sum += __shfl_xor(sum, 1);
      sum += __shfl_xor(sum, 2);
      sum += __shfl_xor(sum, 4);
      sum += __shfl_xor(sum, 8);
      lrow[r] = lrow[r]*f[r] + sum;
    }
#pragma unroll
    for (int n = 0; n < 8; ++n)
#pragma unroll
      for (int r = 0; r < 4; ++r) o[n][r] *= f[r];
    __builtin_amdgcn_s_setprio(1);
#pragma unroll
    for (int kk = 0; kk < 2; ++kk) {
      int prow = l15, pslot = kk*4 + l4;
      bf16x8 pf = *(const bf16x8*)(Pw + prow*128 + ((pslot ^ (prow & 7)) << 4));
#pragma unroll
      for (int n = 0; n < 8; ++n) {
        bf16x8 vf = *(const bf16x8*)(Vp + (size_t)(n*16 + l15)*S_ + kvb + kk*32 + l4*8);
        o[n] = __builtin_amdgcn_mfma_f32_16x16x32_bf16(pf, vf, o[n], 0, 0, 0);
      }
    }
    __builtin_amdgcn_s_setprio(0);
  }
#pragma unroll
  for (int n = 0; n < 8; ++n)
#pragma unroll
    for (int r = 0; r < 4; ++r) {
      int srow = qrow0 + l4*4 + r;
      AOh[(size_t)srow * (H_*HD_) + n*16 + l15] = f2bf(o[n][r] / lrow[r]);
    }
}

__global__ __launch_bounds__(128) void k_attn(
    const u16* __restrict__ Q, const u16* __restrict__ Kc,
    const u16* __restrict__ Vt, u16* __restrict__ AO)
{
  int w = threadIdx.x >> 6, lane = threadIdx.x & 63;
  int pairIdx = blockIdx.x * 2 + w;           // 0..31
  int h = blockIdx.y, b = blockIdx.z, g = h >> 2;
  const u16* Qh = Q  + ((size_t)b*H_   + h) * S_ * HD_;
  const u16* Kp = Kc + ((size_t)b*KVH_ + g) * S_ * HD_;
  const u16* Vp = Vt + ((size_t)b*KVH_ + g) * (size_t)HD_ * S_;   // [HD][S]
  u16* AOh = AO + ((size_t)b*S_) * (H_*HD_) + h*HD_;
  __shared__ u16 Pl[2][1024];
  char* Pw = (char*)&Pl[w][0];

  attn_chunk(pairIdx,      Qh, Kp, Vp, AOh, lane, Pw);
  attn_chunk(63 - pairIdx, Qh, Kp, Vp, AOh, lane, Pw);
}

extern "C" void kernel_launch(void* const* d_in, const int* in_sizes, int n_in,
                              void* d_out, int out_size, void* d_ws, size_t ws_size,
                              hipStream_t stream) {
  (void)in_sizes; (void)n_in; (void)out_size; (void)ws_size;
  const float* x   = (const float*)d_in[0];
  const int*   sid = (const int*)  d_in[1];
  // d_in[2] = cache (dead), d_in[3] = mask (dead: causal re-derived)
  const float* Wq  = (const float*)d_in[4];
  const float* bq  = (const float*)d_in[5];
  const float* Wk  = (const float*)d_in[6];
  const float* bk  = (const float*)d_in[7];
  const float* Wv  = (const float*)d_in[8];
  const float* bv  = (const float*)d_in[9];
  const float* Wo  = (const float*)d_in[10];
  float* out = (float*)d_out;

  char* ws = (char*)d_ws;
  u16*   xb   = (u16*)  (ws);                    // 16 MB (aliased by AO later)
  u16*   WB   = (u16*)  (ws + 16777216);         // 48 MB  [6144][4096]
  u16*   WoT  = (u16*)  (ws + 67108864);         // 32 MB  [4096][4096]
  float* Cq   = (float*)(ws + 100663296);        // 48 MB  [2048][6144]
  u16*   qb   = (u16*)  (ws + 150994944);        // 16 MB  [B][H][S][HD]
  u16*   kb   = (u16*)  (ws + 167772160);        //  4 MB  [B][KVH][S][HD]
  u16*   vb   = (u16*)  (ws + 171966464);        //  4 MB
  u16*   VT   = (u16*)  (ws + 176160768);        //  4 MB  [B][KVH][HD][S]
  float* cosd = (float*)(ws + 180355072);        // 256 KB
  float* sind = (float*)(ws + 180617216);        // 256 KB (total ~181 MB)
  u16*   AO   = xb;                              // attention output reuses xb

  dim3 tb(32, 8);
  k_convert<<<8192, 256, 0, stream>>>(x, xb, (2048*4096)/4);
  k_transpose_w<<<dim3(128,128), tb, 0, stream>>>(Wq, WB, 4096, 4096);
  k_transpose_w<<<dim3( 32,128), tb, 0, stream>>>(Wk, WB + (size_t)4096*4096, 4096, 1024);
  k_transpose_w<<<dim3( 32,128), tb, 0, stream>>>(Wv, WB + (size_t)5120*4096, 4096, 1024);
  k_transpose_w<<<dim3(128,128), tb, 0, stream>>>(Wo, WoT, 4096, 4096);
  k_rope<<<256, 256, 0, stream>>>(sid, cosd, sind);
  k_gemm3<256><<<192, 512, 0, stream>>>(xb, WB, Cq, NQKV, 4096);
  k_pack<<<2048, 256, 0, stream>>>(Cq, bq, bk, bv, cosd, sind, qb, kb, vb);
  k_transpose_v<<<dim3(32,4,16), tb, 0, stream>>>(vb, VT);
  k_attn<<<dim3(16,32,2), 128, 0, stream>>>(qb, kb, VT, AO);
  k_gemm3<128><<<256, 512, 0, stream>>>(AO, WoT, out, 4096, 4096);
}